// Round 2
// baseline (92.844 us; speedup 1.0000x reference)
//
#include <hip/hip_runtime.h>
#include <math.h>

// ---------------- geometry ----------------
// pixels m in [0,784) of a 28x28 image; chunk = 4 consecutive pixels (float4).
// Real chunks: 196. Padded to 208 chunks (= 16 pixel-splits x 13 chunks) with
// zero table records, so the main loop is branch-free.
#define NCHUNK 208
#define NPB 16
#define CHPW 13   // chunks per wave = NCHUNK / NPB

struct c2 { float re, im; };
__device__ inline c2 cmul(c2 a, c2 b){ return {a.re*b.re - a.im*b.im, a.re*b.im + a.im*b.re}; }
__device__ inline c2 cadd(c2 a, c2 b){ return {a.re+b.re, a.im+b.im}; }

__device__ inline void su2_alpha_beta(const float* __restrict__ params, float* Aq, float* Bq) {
    #pragma unroll
    for (int q = 0; q < 4; ++q) {
        c2 m00 = {1.f, 0.f}, m01 = {0.f, 0.f}, m10 = {0.f, 0.f}, m11 = {1.f, 0.f};
        #pragma unroll
        for (int d = 0; d < 4; ++d) {
            float rz1 = params[(d * 4 + q) * 3 + 0];
            float ry  = params[(d * 4 + q) * 3 + 1];
            float rz2 = params[(d * 4 + q) * 3 + 2];
            float c  = __cosf(0.5f * ry),  s  = __sinf(0.5f * ry);
            c2 ph1  = { __cosf(0.5f * rz1), -__sinf(0.5f * rz1) };
            c2 ph1c = { ph1.re, -ph1.im };
            c2 ph2  = { __cosf(0.5f * rz2), -__sinf(0.5f * rz2) };
            c2 ph2c = { ph2.re, -ph2.im };
            c2 d00 = cmul(ph2,  { c * ph1.re,  c * ph1.im });
            c2 d01 = cmul(ph2,  {-s * ph1c.re, -s * ph1c.im});
            c2 d10 = cmul(ph2c, { s * ph1.re,  s * ph1.im });
            c2 d11 = cmul(ph2c, { c * ph1c.re, c * ph1c.im});
            c2 n00 = cadd(cmul(d00, m00), cmul(d01, m10));
            c2 n01 = cadd(cmul(d00, m01), cmul(d01, m11));
            c2 n10 = cadd(cmul(d10, m00), cmul(d11, m10));
            c2 n11 = cadd(cmul(d10, m01), cmul(d11, m11));
            m00 = n00; m01 = n01; m10 = n10; m11 = n11;
        }
        float n00 = m00.re*m00.re + m00.im*m00.im;
        float n10 = m10.re*m10.re + m10.im*m10.im;
        float n01 = m01.re*m01.re + m01.im*m01.im;
        float n11 = m11.re*m11.re + m11.im*m11.im;
        Aq[q] = 0.5f * (n00 - n10 - n01 + n11);
        Bq[q] = (m00.re*m01.re + m00.im*m01.im) - (m10.re*m11.re + m10.im*m11.im);
    }
}

// K1: build table tab[208 chunks][12 float4]:
//   slot 0 = alpha for the 4 pixels, slot 1 = beta, slot 2+cl = w[cl] (permuted).
// grid 13 x 64; block b covers chunks [16b, 16b+16).
__global__ __launch_bounds__(64) void k1_table(
    const float* __restrict__ params, const float* __restrict__ w,
    float4* __restrict__ tab4)
{
    float Aq[4], Bq[4];
    su2_alpha_beta(params, Aq, Bq);
    int t = threadIdx.x, b = blockIdx.x;
    #pragma unroll
    for (int k = 0; k < 3; ++k) {
        int j    = t + 64 * k;          // 0..191 -> (chunk offset, slot)
        int ch   = b * 16 + (j / 12);
        int slot = j % 12;
        float v[4];
        #pragma unroll
        for (int e = 0; e < 4; ++e) {
            int px = ch * 4 + e;
            float val = 0.f;
            if (px < 784) {
                int r = px / 28, col = px - 28 * r;
                int q = ((r & 1) << 1) | (col & 1);
                if (slot == 0)      val = Aq[q];
                else if (slot == 1) val = Bq[q];
                else {
                    int pi = r >> 1, pj = col >> 1;
                    int f  = (pi * 14 + pj) * 4 + q;
                    val = w[(slot - 2) * 784 + f];
                }
            }
            v[e] = val;
        }
        tab4[ch * 12 + slot] = make_float4(v[0], v[1], v[2], v[3]);
    }
}

// K2: one wave per block. lane = sample. block = (sample-group, pixel-split).
// partial[pb][s][10] = sum over this split's 52 pixels of z*w.
__global__ __launch_bounds__(64) void k2_main(
    const float* __restrict__ x, const float4* __restrict__ tab4,
    float* __restrict__ partial, int Bn)
{
    int bid  = blockIdx.x;
    int pb   = bid & (NPB - 1);
    int sg   = bid >> 4;
    int lane = threadIdx.x;
    int s    = sg * 64 + lane;
    if (s >= Bn) s = Bn - 1;            // clamp (Bn is a multiple of 64 anyway)

    const float4* x4 = (const float4*)x;
    size_t xbase = (size_t)s * 196;
    int ch0 = pb * CHPW;

    float acc[10];
    #pragma unroll
    for (int c = 0; c < 10; ++c) acc[c] = 0.f;

    #pragma unroll
    for (int i = 0; i < CHPW; ++i) {
        int ch  = ch0 + i;               // wave-uniform -> scalar table loads
        int chx = ch < 196 ? ch : 195;   // pad chunks: table is zero, x just must not fault
        float4 xv = x4[xbase + chx];
        float4 al = tab4[ch * 12 + 0];
        float4 be = tab4[ch * 12 + 1];
        float z0 = fmaf(al.x, __cosf(xv.x), be.x * __sinf(xv.x));
        float z1 = fmaf(al.y, __cosf(xv.y), be.y * __sinf(xv.y));
        float z2 = fmaf(al.z, __cosf(xv.z), be.z * __sinf(xv.z));
        float z3 = fmaf(al.w, __cosf(xv.w), be.w * __sinf(xv.w));
        #pragma unroll
        for (int cl = 0; cl < 10; ++cl) {
            float4 wv = tab4[ch * 12 + 2 + cl];
            acc[cl] = fmaf(z0, wv.x, acc[cl]);
            acc[cl] = fmaf(z1, wv.y, acc[cl]);
            acc[cl] = fmaf(z2, wv.z, acc[cl]);
            acc[cl] = fmaf(z3, wv.w, acc[cl]);
        }
    }

    int so = sg * 64 + lane;
    if (so < Bn) {
        float2* p2 = (float2*)(partial + ((size_t)pb * Bn + so) * 10);
        #pragma unroll
        for (int c = 0; c < 5; ++c) p2[c] = make_float2(acc[2*c], acc[2*c+1]);
    }
}

// K3: sum the 16 partials + bias, log_softmax, write out.
__global__ __launch_bounds__(256) void k3_reduce(
    const float* __restrict__ partial, const float* __restrict__ bias,
    float* __restrict__ out, int Bn)
{
    int s = blockIdx.x * 256 + threadIdx.x;
    if (s >= Bn) return;
    float l[10];
    #pragma unroll
    for (int c = 0; c < 10; ++c) l[c] = bias[c];
    #pragma unroll
    for (int pb = 0; pb < NPB; ++pb) {
        const float2* p2 = (const float2*)(partial + ((size_t)pb * Bn + s) * 10);
        #pragma unroll
        for (int c = 0; c < 5; ++c) {
            float2 v = p2[c];
            l[2*c]   += v.x;
            l[2*c+1] += v.y;
        }
    }
    float mx = l[0];
    #pragma unroll
    for (int c = 1; c < 10; ++c) mx = fmaxf(mx, l[c]);
    float sum = 0.f;
    #pragma unroll
    for (int c = 0; c < 10; ++c) sum += __expf(l[c] - mx);
    float lse = mx + __logf(sum);
    float2* o2 = (float2*)(out + (size_t)s * 10);
    #pragma unroll
    for (int c = 0; c < 5; ++c) o2[c] = make_float2(l[2*c] - lse, l[2*c+1] - lse);
}

extern "C" void kernel_launch(void* const* d_in, const int* in_sizes, int n_in,
                              void* d_out, int out_size, void* d_ws, size_t ws_size,
                              hipStream_t stream) {
    const float* x      = (const float*)d_in[0];
    const float* params = (const float*)d_in[1];
    const float* w      = (const float*)d_in[2];
    const float* bias   = (const float*)d_in[3];
    float* out = (float*)d_out;
    int Bn = in_sizes[0] / 784;

    float* tab     = (float*)d_ws;                         // 208*12*4 floats = 39936 B
    float* partial = (float*)((char*)d_ws + 40960);        // 16*Bn*10 floats

    k1_table<<<13, 64, 0, stream>>>(params, w, (float4*)tab);

    int nsg = (Bn + 63) / 64;
    k2_main<<<nsg * NPB, 64, 0, stream>>>(x, (const float4*)tab, partial, Bn);

    k3_reduce<<<(Bn + 255) / 256, 256, 0, stream>>>(partial, bias, out, Bn);
}